// Round 1
// baseline (188.926 us; speedup 1.0000x reference)
//
#include <hip/hip_runtime.h>

#define TILE      4096   // positions per block
#define NTHREADS  256
#define PER_ITER  (NTHREADS * 2)   // 512 positions per iteration

// log(0.1), log(0.9) — note ALPHA=0.1, BETA=0.9 makes log_a==log_1b, log_1a==log_b
#define L1C (-2.3025850929940457f)
#define L9C (-0.10536051565782628f)

__global__ __launch_bounds__(NTHREADS) void ekl_main(
    const float* __restrict__ posterior,
    const int*   __restrict__ length,
    double*      __restrict__ partial,
    int S, int chunks)
{
    const int b      = blockIdx.y;
    const int chunk  = blockIdx.x;
    const int cstart = chunk * TILE;
    const int tid    = threadIdx.x;
    const int pidx   = b * chunks + chunk;
    const int len    = length[b];

    // Whole chunk past this row's length: contributes nothing.
    if (cstart > 0 && cstart >= len) {
        if (tid == 0) partial[pidx] = 0.0;
        return;
    }

    const float* row = posterior + (size_t)b * (size_t)S * 2u;
    float acc = 0.0f;

    #pragma unroll
    for (int j = 0; j < TILE / PER_ITER; ++j) {
        const int s0 = cstart + j * PER_ITER + 2 * tid;   // even
        const bool act = (s0 == 0) || (s0 < len);
        if (act) {
            // curr pair: positions s0, s0+1 (16B aligned: offset 8*s0)
            float4 c;
            if (s0 + 1 < S) {
                c = *(const float4*)(row + 2 * (size_t)s0);
            } else {
                float2 t = *(const float2*)(row + 2 * (size_t)s0);
                c.x = t.x; c.y = t.y; c.z = 1.0f; c.w = 1.0f;
            }

            // term at s0
            const float l0x = logf(c.x), l0y = logf(c.y);
            const float A0 = c.y * (l0y - L9C) + c.x * (l0x - L1C);
            const float B0 = c.y * (l0y - L1C) + c.x * (l0x - L9C);
            if (s0 == 0) {
                acc += B0;                         // "first" term, always counted
            } else {
                // past = position s0-1 (overlapping 8B load, L1 hit)
                const float2 pv = *(const float2*)(row + 2 * (size_t)s0 - 2);
                acc += pv.y * A0 + pv.x * B0;
            }

            // term at s1 = s0+1 (past = curr at s0, already in regs)
            if (s0 + 1 < len) {
                const float l1x = logf(c.z), l1y = logf(c.w);
                const float A1 = c.w * (l1y - L9C) + c.z * (l1x - L1C);
                const float B1 = c.w * (l1y - L1C) + c.z * (l1x - L9C);
                acc += c.y * A1 + c.x * B1;
            }
        }
    }

    // wave (64-lane) shuffle reduce, then cross-wave via LDS in double
    #pragma unroll
    for (int off = 32; off > 0; off >>= 1)
        acc += __shfl_down(acc, off, 64);

    __shared__ double wsum[NTHREADS / 64];
    if ((tid & 63) == 0) wsum[tid >> 6] = (double)acc;
    __syncthreads();
    if (tid == 0) {
        double t = 0.0;
        #pragma unroll
        for (int i = 0; i < NTHREADS / 64; ++i) t += wsum[i];
        partial[pidx] = t;
    }
}

__global__ __launch_bounds__(256) void ekl_reduce(
    const double* __restrict__ partial, int n,
    float* __restrict__ out, double invB)
{
    double acc = 0.0;
    for (int i = threadIdx.x; i < n; i += 256) acc += partial[i];
    #pragma unroll
    for (int off = 32; off > 0; off >>= 1)
        acc += __shfl_down(acc, off, 64);
    __shared__ double wsum[4];
    if ((threadIdx.x & 63) == 0) wsum[threadIdx.x >> 6] = acc;
    __syncthreads();
    if (threadIdx.x == 0)
        out[0] = (float)((wsum[0] + wsum[1] + wsum[2] + wsum[3]) * invB);
}

extern "C" void kernel_launch(void* const* d_in, const int* in_sizes, int n_in,
                              void* d_out, int out_size, void* d_ws, size_t ws_size,
                              hipStream_t stream)
{
    const float* posterior = (const float*)d_in[0];
    const int*   length    = (const int*)d_in[1];

    const int B = in_sizes[1];                       // 512
    const int S = (int)((long long)in_sizes[0] / ((long long)B * 2)); // 32768
    const int chunks = (S + TILE - 1) / TILE;        // 8

    double* partial = (double*)d_ws;                 // B*chunks doubles (32 KiB)

    dim3 grid(chunks, B);
    ekl_main<<<grid, NTHREADS, 0, stream>>>(posterior, length, partial, S, chunks);
    ekl_reduce<<<1, 256, 0, stream>>>(partial, B * chunks, (float*)d_out,
                                      1.0 / (double)B);
}

// Round 2
// 187.959 us; speedup vs baseline: 1.0051x; 1.0051x over previous
//
#include <hip/hip_runtime.h>

#define TILE      4096   // positions per block
#define NTHREADS  256
#define PER_ITER  (NTHREADS * 2)   // 512 positions per block-iteration

// ALPHA=0.1, BETA=0.9 -> log_a == log_1b == log(0.1), log_1a == log_b == log(0.9)
#define L1C (-2.3025850929940457f)   // log(0.1)
#define L9C (-0.10536051565782628f)  // log(0.9)

// NOTE: assumes S is even and TILE | S (true for S=32768); all float4 loads
// inside a chunk are in-bounds regardless of length (row has S positions).
__global__ __launch_bounds__(NTHREADS) void ekl_main(
    const float* __restrict__ posterior,
    const int*   __restrict__ length,
    double*      __restrict__ partial,
    int S, int chunks)
{
    const int b      = blockIdx.y;
    const int chunk  = blockIdx.x;
    const int cstart = chunk * TILE;
    const int tid    = threadIdx.x;
    const int pidx   = b * chunks + chunk;
    const int len    = length[b];

    // Whole chunk past this row's length: contributes nothing (skip its HBM reads).
    if (cstart > 0 && cstart >= len) {
        if (tid == 0) partial[pidx] = 0.0;
        return;
    }

    const float* row = posterior + (size_t)b * (size_t)S * 2u;
    float acc = 0.0f;

    #pragma unroll
    for (int j = 0; j < TILE / PER_ITER; ++j) {
        const int s0 = cstart + j * PER_ITER + 2 * tid;   // even position
        const bool act = (s0 < len) || (s0 == 0);

        // One coalesced 16B load per thread: positions s0, s0+1.
        float4 c = make_float4(1.0f, 1.0f, 1.0f, 1.0f);
        if (act) c = *(const float4*)(row + 2 * (size_t)s0);

        // "past" for s0 = position s0-1 = left lane's (c.z, c.w).
        // act is monotone non-increasing along lanes (except s0==0, which
        // doesn't consume pv), so garbage only flows to inactive consumers.
        float pvx = __shfl_up(c.z, 1, 64);
        float pvy = __shfl_up(c.w, 1, 64);

        if (act) {
            if ((tid & 63) == 0 && s0 > 0) {               // wave boundary
                const float2 t = *(const float2*)(row + 2 * (size_t)s0 - 2);
                pvx = t.x; pvy = t.y;
            }

            const float l0x = __logf(c.x), l0y = __logf(c.y);
            const float A0 = c.y * (l0y - L9C) + c.x * (l0x - L1C);
            const float B0 = c.y * (l0y - L1C) + c.x * (l0x - L9C);
            acc += (s0 == 0) ? B0 : (pvy * A0 + pvx * B0);

            if (s0 + 1 < len) {                            // term at s0+1, past in regs
                const float l1x = __logf(c.z), l1y = __logf(c.w);
                acc += c.y * (c.w * (l1y - L9C) + c.z * (l1x - L1C))
                     + c.x * (c.w * (l1y - L1C) + c.z * (l1x - L9C));
            }
        }
    }

    // 64-lane shuffle reduce, then cross-wave in double via LDS.
    #pragma unroll
    for (int off = 32; off > 0; off >>= 1)
        acc += __shfl_down(acc, off, 64);

    __shared__ double wsum[NTHREADS / 64];
    if ((tid & 63) == 0) wsum[tid >> 6] = (double)acc;
    __syncthreads();
    if (tid == 0) {
        double t = 0.0;
        #pragma unroll
        for (int i = 0; i < NTHREADS / 64; ++i) t += wsum[i];
        partial[pidx] = t;
    }
}

#define RTHREADS 1024
__global__ __launch_bounds__(RTHREADS) void ekl_reduce(
    const double* __restrict__ partial, int n,
    float* __restrict__ out, double invB)
{
    double acc = 0.0;
    for (int i = threadIdx.x; i < n; i += RTHREADS) acc += partial[i];
    #pragma unroll
    for (int off = 32; off > 0; off >>= 1)
        acc += __shfl_down(acc, off, 64);
    __shared__ double wsum[RTHREADS / 64];
    if ((threadIdx.x & 63) == 0) wsum[threadIdx.x >> 6] = acc;
    __syncthreads();
    if (threadIdx.x == 0) {
        double t = 0.0;
        #pragma unroll
        for (int i = 0; i < RTHREADS / 64; ++i) t += wsum[i];
        out[0] = (float)(t * invB);
    }
}

extern "C" void kernel_launch(void* const* d_in, const int* in_sizes, int n_in,
                              void* d_out, int out_size, void* d_ws, size_t ws_size,
                              hipStream_t stream)
{
    const float* posterior = (const float*)d_in[0];
    const int*   length    = (const int*)d_in[1];

    const int B = in_sizes[1];                                        // 512
    const int S = (int)((long long)in_sizes[0] / ((long long)B * 2)); // 32768
    const int chunks = (S + TILE - 1) / TILE;                         // 8

    double* partial = (double*)d_ws;                                  // B*chunks doubles

    dim3 grid(chunks, B);
    ekl_main<<<grid, NTHREADS, 0, stream>>>(posterior, length, partial, S, chunks);
    ekl_reduce<<<1, RTHREADS, 0, stream>>>(partial, B * chunks, (float*)d_out,
                                           1.0 / (double)B);
}